// Round 7
// baseline (489.348 us; speedup 1.0000x reference)
//
#include <hip/hip_runtime.h>
#include <hip/hip_cooperative_groups.h>

namespace cg = cooperative_groups;

#define NS 65536      // stocks
#define HID 512       // hidden
#define NE 128        // industries
#define NBLK 256      // blocks (1 per CU)
#define NTHR 1024     // threads per block (16 waves)
#define NEG 0.01f     // LeakyReLU slope

// Single persistent cooperative kernel; phases separated by grid.sync().
// Phase A: decode one-hot -> ind, per-block hist -> bhist      (no global atomics)
// Phase C: block-local scan of bhist -> offL/totL/baseL; scatter -> sorted
// Phase D: per-industry row-sum of e_s (PC=2 chunks) -> partial (register acc)
// Phase F: blocks 0..127: edge GEMM ef[e] = Binv*(partial0+partial1)[e] @ W
// Phase H: out = LeakyReLU(ef[ind[s]] + bias), grid-stride float4
__global__ __launch_bounds__(NTHR, 4) void k_fused(
    const float* __restrict__ e_s,
    const int*   __restrict__ im,
    const float* __restrict__ W,
    const float* __restrict__ bias,
    float*       __restrict__ out,
    int*         __restrict__ ind,
    int*         __restrict__ sorted,
    int*         __restrict__ bhist,
    float*       __restrict__ partial,
    float*       __restrict__ ef)
{
    cg::grid_group grid = cg::this_grid();
    const int b = blockIdx.x, t = threadIdx.x;

    __shared__ int    lind[256];
    __shared__ int    lhist[NE];
    __shared__ int    totL[NE];
    __shared__ int    offL[NE + 1];
    __shared__ int    baseL[NE];
    __shared__ int    cnt[NE];
    __shared__ int    rows[1024];
    __shared__ float4 red[NTHR];     // 16 KB; reused as float[2048] in gemm
    __shared__ float  aL[HID];

    // ---- Phase A: decode + per-block histogram ----
    if (t < NE) lhist[t] = 0;
    __syncthreads();
    {
        const int4* p = reinterpret_cast<const int4*>(im) + (size_t)b * 8192;
#pragma unroll
        for (int j = t; j < 8192; j += NTHR) {   // 256 rows x 32 int4
            int4 v = p[j];
            int s = j >> 5;           // local row
            int c = (j & 31) << 2;    // column of v.x
            if (v.x == 1) lind[s] = c;
            if (v.y == 1) lind[s] = c + 1;
            if (v.z == 1) lind[s] = c + 2;
            if (v.w == 1) lind[s] = c + 3;
        }
    }
    __syncthreads();
    if (t < 256) {
        int e = lind[t];
        ind[b * 256 + t] = e;
        atomicAdd(&lhist[e], 1);      // LDS atomic only
    }
    __syncthreads();
    if (t < NE) bhist[b * NE + t] = lhist[t];

    __threadfence();
    grid.sync();

    // ---- Phase C: block-local scan + scatter ----
    if (t < NE) {
        int base = 0, tot = 0;
#pragma unroll 8
        for (int b2 = 0; b2 < NBLK; ++b2) {
            int v = bhist[b2 * NE + t];   // coalesced 512B per b2, L2-hot
            if (b2 < b) base += v;
            tot += v;
        }
        totL[t] = tot;
        baseL[t] = base;
        cnt[t] = 0;
    }
    __syncthreads();
    if (t == 0) {
        int a = 0;
#pragma unroll 8
        for (int k = 0; k < NE; ++k) { offL[k] = a; a += totL[k]; }
        offL[NE] = a;
    }
    __syncthreads();
    if (t < NE) baseL[t] += offL[t];
    __syncthreads();
    if (t < 256) {
        int e = ind[b * 256 + t];
        int p = atomicAdd(&cnt[e], 1);   // LDS atomic
        sorted[baseL[e] + p] = b * 256 + t;
    }

    __threadfence();
    grid.sync();

    // ---- Phase D: per-industry aggregation (2 chunks/industry) ----
    {
        const int e = b >> 1, c = b & 1;
        const int s0 = offL[e], s1 = offL[e + 1];   // offL persists in LDS
        const int len = s1 - s0;
        const int i0 = s0 + (c * len) / 2;
        const int i1 = s0 + ((c + 1) * len) / 2;
        const int seg = i1 - i0;
        const int stage = (seg < 1024) ? seg : 1024;   // expected ~256
        for (int k = t; k < stage; k += NTHR) rows[k] = sorted[i0 + k];
        __syncthreads();
        const int g = t >> 7;        // 8 groups of 128 threads
        const int l = t & 127;       // float4 column
        float4 acc = {0.f, 0.f, 0.f, 0.f};
#pragma unroll 2
        for (int i = i0 + g; i < i1; i += 8) {
            int idx = i - i0;
            int row = (idx < stage) ? rows[idx] : sorted[i];
            float4 v = reinterpret_cast<const float4*>(e_s + (size_t)row * HID)[l];
            acc.x += v.x; acc.y += v.y; acc.z += v.z; acc.w += v.w;
        }
        red[t] = acc;
        __syncthreads();
        if (g == 0) {
            float4 a = red[l];
#pragma unroll
            for (int q = 1; q < 8; ++q) {
                float4 o = red[l + q * 128];
                a.x += o.x; a.y += o.y; a.z += o.z; a.w += o.w;
            }
            reinterpret_cast<float4*>(partial + ((size_t)c * NE + e) * HID)[l] = a;
        }
    }

    __threadfence();
    grid.sync();

    // ---- Phase F: edge GEMM (blocks 0..127 only) ----
    if (b < NE) {
        const int e = b;
        if (t < HID) aL[t] = partial[(size_t)e * HID + t]
                           + partial[((size_t)NE + e) * HID + t];
        __syncthreads();
        const int j  = t & (HID - 1);
        const int h  = t >> 9;            // K-half: 0 or 1
        const int k0 = h * 256;
        float acc = 0.0f;
#pragma unroll 8
        for (int k = k0; k < k0 + 256; ++k)
            acc += aL[k] * W[k * HID + j];   // aL: LDS broadcast; W: coalesced
        float* redf = reinterpret_cast<float*>(red);
        redf[t] = acc;
        __syncthreads();
        if (t < HID) {
            float tot  = redf[t] + redf[t + HID];
            float binv = (totL[e] > 0) ? 1.0f / (float)totL[e] : 0.0f;
            ef[(size_t)e * HID + t] = tot * binv;
        }
    }

    __threadfence();
    grid.sync();

    // ---- Phase H: output ----
    {
        const int total = NS * (HID / 4);   // float4 elements
        for (int i = b * NTHR + t; i < total; i += NBLK * NTHR) {
            int s  = i >> 7;                // 128 float4 per row
            int c4 = i & 127;
            int e  = ind[s];
            float4 v  = reinterpret_cast<const float4*>(ef + (size_t)e * HID)[c4];
            float4 bb = reinterpret_cast<const float4*>(bias)[c4];
            v.x += bb.x; v.y += bb.y; v.z += bb.z; v.w += bb.w;
            v.x = (v.x >= 0.0f) ? v.x : NEG * v.x;
            v.y = (v.y >= 0.0f) ? v.y : NEG * v.y;
            v.z = (v.z >= 0.0f) ? v.z : NEG * v.z;
            v.w = (v.w >= 0.0f) ? v.w : NEG * v.w;
            reinterpret_cast<float4*>(out)[i] = v;
        }
    }
}

extern "C" void kernel_launch(void* const* d_in, const int* in_sizes, int n_in,
                              void* d_out, int out_size, void* d_ws, size_t ws_size,
                              hipStream_t stream) {
    const float* e_s  = (const float*)d_in[0];
    const int*   im   = (const int*)d_in[1];
    const float* W    = (const float*)d_in[2];
    const float* bias = (const float*)d_in[3];
    float* out = (float*)d_out;

    char* ws = (char*)d_ws;
    // Lifetime-overlaid layout, total 1,048,576 B (same footprint as before):
    //   [0,    256K) ind      (A -> H)
    //   [256K, 512K) sorted   (C -> D)  overlaid by ef (F -> H)
    //   [512K, 640K) bhist    (A -> C)  overlaid by
    //   [512K,1024K) partial  (D -> F)  (bhist dead before D writes)
    int*   ind     = (int*)(ws + 0);
    int*   sorted  = (int*)(ws + 262144);
    float* ef      = (float*)(ws + 262144);
    int*   bhist   = (int*)(ws + 524288);
    float* partial = (float*)(ws + 524288);

    void* args[] = { (void*)&e_s, (void*)&im, (void*)&W, (void*)&bias, (void*)&out,
                     (void*)&ind, (void*)&sorted, (void*)&bhist, (void*)&partial,
                     (void*)&ef };
    hipLaunchCooperativeKernel((const void*)k_fused, dim3(NBLK), dim3(NTHR),
                               args, 0, stream);
}

// Round 8
// 98.367 us; speedup vs baseline: 4.9747x; 4.9747x over previous
//
#include <hip/hip_runtime.h>

#define NS 65536      // stocks
#define HID 512       // hidden
#define NE 128        // industries
#define NB 256        // blocks in find/scatter (256 stocks each)
#define PC 2          // chunks per industry (aggregate & gemm_out)
#define NEG 0.01f     // LeakyReLU slope

// ---------------------------------------------------------------------------
// K1: decode one-hot rows -> ind[s]; per-block LDS histogram -> bhist.
__global__ __launch_bounds__(256) void k_find(const int* __restrict__ im,
                                              int* __restrict__ ind,
                                              int* __restrict__ bhist) {
    __shared__ int lind[256];
    __shared__ int lhist[NE];
    const int b = blockIdx.x, t = threadIdx.x;
    if (t < NE) lhist[t] = 0;
    const int4* p = reinterpret_cast<const int4*>(im) + (size_t)b * 8192;
#pragma unroll
    for (int j = t; j < 8192; j += 256) {   // 256 rows x 32 int4
        int4 v = p[j];
        int s = j >> 5;          // local row
        int c = (j & 31) << 2;   // column of v.x
        if (v.x == 1) lind[s] = c;
        if (v.y == 1) lind[s] = c + 1;
        if (v.z == 1) lind[s] = c + 2;
        if (v.w == 1) lind[s] = c + 3;
    }
    __syncthreads();
    int e = lind[t];
    ind[b * 256 + t] = e;
    atomicAdd(&lhist[e], 1);     // LDS atomic only
    __syncthreads();
    if (t < NE) bhist[b * NE + t] = lhist[t];
}

// ---------------------------------------------------------------------------
// K2: scatter with inlined scan (every block recomputes prefix from bhist,
// L2-resident). Block 0 publishes off[129]. LDS atomics only.
__global__ __launch_bounds__(256) void k_scatter(const int* __restrict__ ind,
                                                 const int* __restrict__ bhist,
                                                 int* __restrict__ sorted,
                                                 int* __restrict__ off) {
    __shared__ int totL[NE];
    __shared__ int offL[NE + 1];
    __shared__ int baseL[NE];
    __shared__ int cnt[NE];
    const int b = blockIdx.x, t = threadIdx.x;
    if (t < NE) {
        int base = 0, tot = 0;
#pragma unroll 8
        for (int b2 = 0; b2 < NB; ++b2) {
            int v = bhist[b2 * NE + t];   // coalesced 512B per b2
            if (b2 < b) base += v;
            tot += v;
        }
        totL[t] = tot;
        baseL[t] = base;
        cnt[t] = 0;
    }
    __syncthreads();
    if (t == 0) {
        int a = 0;
#pragma unroll 8
        for (int k = 0; k < NE; ++k) { offL[k] = a; a += totL[k]; }
        offL[NE] = a;
    }
    __syncthreads();
    if (t < NE) baseL[t] += offL[t];
    if (b == 0) {
        if (t < NE) off[t] = offL[t];
        if (t == 0) off[NE] = offL[NE];
    }
    __syncthreads();
    int e = ind[b * 256 + t];
    int p = atomicAdd(&cnt[e], 1);   // LDS atomic
    sorted[baseL[e] + p] = b * 256 + t;
}

// ---------------------------------------------------------------------------
// K3: per-industry row-sum of e_s. Grid = NE*PC blocks x 1024 threads.
// Group g = t>>7 (8 groups) sums every-8th row; lane l = t&127 owns float4
// column l. Writes disjoint partial[c][e][:]. No atomics.
__global__ __launch_bounds__(1024) void k_aggregate(const float* __restrict__ e_s,
                                                    const int* __restrict__ sorted,
                                                    const int* __restrict__ off,
                                                    float* __restrict__ partial) {
    __shared__ int rows[1024];
    __shared__ float4 red[1024];
    const int e = blockIdx.x >> 1;
    const int c = blockIdx.x & 1;
    const int t = threadIdx.x;
    const int s0 = off[e], s1 = off[e + 1];
    const int len = s1 - s0;
    const int i0 = s0 + (c * len) / PC;
    const int i1 = s0 + ((c + 1) * len) / PC;
    const int seg = i1 - i0;
    const int stage = (seg < 1024) ? seg : 1024;   // expected ~256
    for (int k = t; k < stage; k += 1024) rows[k] = sorted[i0 + k];
    __syncthreads();
    const int g = t >> 7;        // wave-uniform
    const int l = t & 127;
    float4 acc = {0.f, 0.f, 0.f, 0.f};
#pragma unroll 2
    for (int i = i0 + g; i < i1; i += 8) {
        int idx = i - i0;
        int row = (idx < stage) ? rows[idx] : sorted[i];   // uniform broadcast
        float4 v = reinterpret_cast<const float4*>(e_s + (size_t)row * HID)[l];
        acc.x += v.x; acc.y += v.y; acc.z += v.z; acc.w += v.w;
    }
    red[t] = acc;
    __syncthreads();
    if (g == 0) {
        float4 a = red[l];
#pragma unroll
        for (int q = 1; q < 8; ++q) {
            float4 o = red[l + q * 128];
            a.x += o.x; a.y += o.y; a.z += o.z; a.w += o.w;
        }
        reinterpret_cast<float4*>(partial + ((size_t)c * NE + e) * HID)[l] = a;
    }
}

// ---------------------------------------------------------------------------
// K4: fused edge-GEMM + output stream. 2 blocks per industry; each block
// recomputes the tiny GEMM for its industry (W is L2-hot, ~0.26 MFLOP),
// builds row = LeakyReLU(ef+bias) ONCE in LDS (identical for all stocks of
// the industry), then streams 2KB rows to its half of the stock list.
__global__ __launch_bounds__(1024) void k_gemm_out(const float* __restrict__ partial,
                                                   const float* __restrict__ W,
                                                   const float* __restrict__ bias,
                                                   const int* __restrict__ sorted,
                                                   const int* __restrict__ off,
                                                   float* __restrict__ out) {
    __shared__ float aL[HID];
    __shared__ float redf[1024];
    __shared__ float rowL[HID];
    const int e = blockIdx.x >> 1;
    const int c = blockIdx.x & 1;
    const int t = threadIdx.x;
    const int s0 = off[e], s1 = off[e + 1];
    const int tot = s1 - s0;

    if (t < HID) aL[t] = partial[(size_t)e * HID + t]
                       + partial[((size_t)NE + e) * HID + t];
    __syncthreads();
    const int j  = t & (HID - 1);
    const int h  = t >> 9;            // K-half: 0 or 1
    const int k0 = h * 256;
    float acc = 0.0f;
#pragma unroll 8
    for (int k = k0; k < k0 + 256; ++k)
        acc += aL[k] * W[k * HID + j];   // aL: LDS broadcast; W: coalesced/L2
    redf[t] = acc;
    __syncthreads();
    if (t < HID) {
        float binv = (tot > 0) ? 1.0f / (float)tot : 0.0f;
        float v = (redf[t] + redf[t + HID]) * binv + bias[t];
        rowL[t] = (v >= 0.0f) ? v : NEG * v;
    }
    __syncthreads();

    // stream the finished row to this block's half of the industry's stocks
    const int i0 = s0 + (c * tot) / PC;
    const int i1 = s0 + ((c + 1) * tot) / PC;
    const int g = t >> 7;        // 8 groups: one row per group per iter
    const int l = t & 127;       // float4 lane within row
    const float4 r4 = reinterpret_cast<const float4*>(rowL)[l];  // in regs
    for (int i = i0 + g; i < i1; i += 8) {
        int s = sorted[i];       // wave-uniform -> scalar load
        reinterpret_cast<float4*>(out + (size_t)s * HID)[l] = r4;
    }
}

extern "C" void kernel_launch(void* const* d_in, const int* in_sizes, int n_in,
                              void* d_out, int out_size, void* d_ws, size_t ws_size,
                              hipStream_t stream) {
    const float* e_s  = (const float*)d_in[0];
    const int*   im   = (const int*)d_in[1];
    const float* W    = (const float*)d_in[2];
    const float* bias = (const float*)d_in[3];
    float* out = (float*)d_out;

    char* ws = (char*)d_ws;
    // Aliased layout (lifetimes disjoint), ~1 MB:
    //   [0,    256K) ind      (K1 -> K2)
    //   [256K, 512K) sorted   (K2 -> K4)
    //   [512K, 640K) bhist    (K1 -> K2) } overlaid by
    //   [512K,1024K) partial  (K3 -> K4) } (bhist dead before K3 writes)
    //   [1024K,+516B) off[129] (K2 -> K3,K4)
    int*   ind     = (int*)(ws + 0);
    int*   sorted  = (int*)(ws + 262144);
    int*   bhist   = (int*)(ws + 524288);
    float* partial = (float*)(ws + 524288);
    int*   off     = (int*)(ws + 1048576);

    k_find     <<<NB, 256, 0, stream>>>(im, ind, bhist);
    k_scatter  <<<NB, 256, 0, stream>>>(ind, bhist, sorted, off);
    k_aggregate<<<NE * PC, 1024, 0, stream>>>(e_s, sorted, off, partial);
    k_gemm_out <<<NE * PC, 1024, 0, stream>>>(partial, W, bias, sorted, off, out);
}

// Round 9
// 80.428 us; speedup vs baseline: 6.0843x; 1.2230x over previous
//
#include <hip/hip_runtime.h>

#define NS 65536      // stocks
#define HID 512       // hidden
#define NE 128        // industries
#define NB 256        // blocks in find/scatter (256 stocks each)
#define PC 2          // chunks per industry (aggregate & gemm_out)
#define NEG 0.01f     // LeakyReLU slope

// ---------------------------------------------------------------------------
// K1: decode one-hot rows -> ind[s]; per-block LDS histogram -> bhist.
// 1024 threads (16 waves/CU) for latency hiding on the 33.5 MB read.
__global__ __launch_bounds__(1024) void k_find(const int* __restrict__ im,
                                               int* __restrict__ ind,
                                               int* __restrict__ bhist) {
    __shared__ int lind[256];
    __shared__ int lhist[NE];
    const int b = blockIdx.x, t = threadIdx.x;
    if (t < NE) lhist[t] = 0;
    const int4* p = reinterpret_cast<const int4*>(im) + (size_t)b * 8192;
#pragma unroll
    for (int j = t; j < 8192; j += 1024) {   // 256 rows x 32 int4, 8 iters
        int4 v = p[j];
        int s = j >> 5;          // local row
        int c = (j & 31) << 2;   // column of v.x
        if (v.x == 1) lind[s] = c;
        if (v.y == 1) lind[s] = c + 1;
        if (v.z == 1) lind[s] = c + 2;
        if (v.w == 1) lind[s] = c + 3;
    }
    __syncthreads();
    if (t < 256) {
        int e = lind[t];
        ind[b * 256 + t] = e;
        atomicAdd(&lhist[e], 1);     // LDS atomic only
    }
    __syncthreads();
    if (t < NE) bhist[b * NE + t] = lhist[t];
}

// ---------------------------------------------------------------------------
// K2: scatter with inlined scan. 1024 threads: the 256-block bhist scan is
// split across 8 groups (32 iters each, deterministic) + LDS reduce.
// Block 0 publishes off[129]. LDS atomics only.
__global__ __launch_bounds__(1024) void k_scatter(const int* __restrict__ ind,
                                                  const int* __restrict__ bhist,
                                                  int* __restrict__ sorted,
                                                  int* __restrict__ off) {
    __shared__ int totG[8][NE];
    __shared__ int baseG[8][NE];
    __shared__ int totL[NE];
    __shared__ int offL[NE + 1];
    __shared__ int baseL[NE];
    __shared__ int cnt[NE];
    const int b = blockIdx.x, t = threadIdx.x;
    const int g = t >> 7;        // group 0..7
    const int e = t & 127;       // industry
    {
        int base = 0, tot = 0;
        const int b2lo = g * 32, b2hi = b2lo + 32;
#pragma unroll 8
        for (int b2 = b2lo; b2 < b2hi; ++b2) {
            int v = bhist[b2 * NE + e];   // coalesced 512B per b2, L2-hot
            if (b2 < b) base += v;
            tot += v;
        }
        totG[g][e] = tot;
        baseG[g][e] = base;
    }
    __syncthreads();
    if (t < NE) {
        int tot = 0, base = 0;
#pragma unroll
        for (int q = 0; q < 8; ++q) { tot += totG[q][t]; base += baseG[q][t]; }
        totL[t] = tot;
        baseL[t] = base;
        cnt[t] = 0;
    }
    __syncthreads();
    if (t == 0) {
        int a = 0;
#pragma unroll 8
        for (int k = 0; k < NE; ++k) { offL[k] = a; a += totL[k]; }
        offL[NE] = a;
    }
    __syncthreads();
    if (t < NE) baseL[t] += offL[t];
    if (b == 0) {
        if (t < NE) off[t] = offL[t];
        if (t == 0) off[NE] = offL[NE];
    }
    __syncthreads();
    if (t < 256) {
        int ee = ind[b * 256 + t];
        int p = atomicAdd(&cnt[ee], 1);   // LDS atomic
        sorted[baseL[ee] + p] = b * 256 + t;
    }
}

// ---------------------------------------------------------------------------
// K3: per-industry row-sum of e_s. Grid = NE*PC blocks x 1024 threads.
// Group g = t>>7 (8 groups) sums every-8th row; lane l = t&127 owns float4
// column l. unroll 4 for deeper memory-level parallelism. No atomics.
__global__ __launch_bounds__(1024) void k_aggregate(const float* __restrict__ e_s,
                                                    const int* __restrict__ sorted,
                                                    const int* __restrict__ off,
                                                    float* __restrict__ partial) {
    __shared__ int rows[1024];
    __shared__ float4 red[1024];
    const int e = blockIdx.x >> 1;
    const int c = blockIdx.x & 1;
    const int t = threadIdx.x;
    const int s0 = off[e], s1 = off[e + 1];
    const int len = s1 - s0;
    const int i0 = s0 + (c * len) / PC;
    const int i1 = s0 + ((c + 1) * len) / PC;
    const int seg = i1 - i0;
    const int stage = (seg < 1024) ? seg : 1024;   // expected ~256
    for (int k = t; k < stage; k += 1024) rows[k] = sorted[i0 + k];
    __syncthreads();
    const int g = t >> 7;        // wave-uniform
    const int l = t & 127;
    float4 acc = {0.f, 0.f, 0.f, 0.f};
#pragma unroll 4
    for (int i = i0 + g; i < i1; i += 8) {
        int idx = i - i0;
        int row = (idx < stage) ? rows[idx] : sorted[i];   // uniform broadcast
        float4 v = reinterpret_cast<const float4*>(e_s + (size_t)row * HID)[l];
        acc.x += v.x; acc.y += v.y; acc.z += v.z; acc.w += v.w;
    }
    red[t] = acc;
    __syncthreads();
    if (g == 0) {
        float4 a = red[l];
#pragma unroll
        for (int q = 1; q < 8; ++q) {
            float4 o = red[l + q * 128];
            a.x += o.x; a.y += o.y; a.z += o.z; a.w += o.w;
        }
        reinterpret_cast<float4*>(partial + ((size_t)c * NE + e) * HID)[l] = a;
    }
}

// ---------------------------------------------------------------------------
// K4: fused edge-GEMM + output stream. 2 blocks per industry; each block
// recomputes the tiny GEMM (W L2-hot), builds row = LeakyReLU(ef+bias) once
// in LDS, then streams 2KB rows to its half of the industry's stock list.
__global__ __launch_bounds__(1024) void k_gemm_out(const float* __restrict__ partial,
                                                   const float* __restrict__ W,
                                                   const float* __restrict__ bias,
                                                   const int* __restrict__ sorted,
                                                   const int* __restrict__ off,
                                                   float* __restrict__ out) {
    __shared__ float aL[HID];
    __shared__ float redf[1024];
    __shared__ float rowL[HID];
    const int e = blockIdx.x >> 1;
    const int c = blockIdx.x & 1;
    const int t = threadIdx.x;
    const int s0 = off[e], s1 = off[e + 1];
    const int tot = s1 - s0;

    if (t < HID) aL[t] = partial[(size_t)e * HID + t]
                       + partial[((size_t)NE + e) * HID + t];
    __syncthreads();
    const int j  = t & (HID - 1);
    const int h  = t >> 9;            // K-half: 0 or 1
    const int k0 = h * 256;
    float acc = 0.0f;
#pragma unroll 8
    for (int k = k0; k < k0 + 256; ++k)
        acc += aL[k] * W[k * HID + j];   // aL: LDS broadcast; W: coalesced/L2
    redf[t] = acc;
    __syncthreads();
    if (t < HID) {
        float binv = (tot > 0) ? 1.0f / (float)tot : 0.0f;
        float v = (redf[t] + redf[t + HID]) * binv + bias[t];
        rowL[t] = (v >= 0.0f) ? v : NEG * v;
    }
    __syncthreads();

    // stream the finished row to this block's half of the industry's stocks
    const int i0 = s0 + (c * tot) / PC;
    const int i1 = s0 + ((c + 1) * tot) / PC;
    const int g = t >> 7;        // 8 groups: one row per group per iter
    const int l = t & 127;       // float4 lane within row
    const float4 r4 = reinterpret_cast<const float4*>(rowL)[l];  // in regs
#pragma unroll 2
    for (int i = i0 + g; i < i1; i += 8) {
        int s = sorted[i];       // wave-uniform -> scalar load, L2-hot
        reinterpret_cast<float4*>(out + (size_t)s * HID)[l] = r4;
    }
}

extern "C" void kernel_launch(void* const* d_in, const int* in_sizes, int n_in,
                              void* d_out, int out_size, void* d_ws, size_t ws_size,
                              hipStream_t stream) {
    const float* e_s  = (const float*)d_in[0];
    const int*   im   = (const int*)d_in[1];
    const float* W    = (const float*)d_in[2];
    const float* bias = (const float*)d_in[3];
    float* out = (float*)d_out;

    char* ws = (char*)d_ws;
    // Aliased layout (lifetimes disjoint), ~1 MB:
    //   [0,    256K) ind      (K1 -> K2)
    //   [256K, 512K) sorted   (K2 -> K4)
    //   [512K, 640K) bhist    (K1 -> K2) } overlaid by
    //   [512K,1024K) partial  (K3 -> K4) } (bhist dead before K3 writes)
    //   [1024K,+516B) off[129] (K2 -> K3,K4)
    int*   ind     = (int*)(ws + 0);
    int*   sorted  = (int*)(ws + 262144);
    int*   bhist   = (int*)(ws + 524288);
    float* partial = (float*)(ws + 524288);
    int*   off     = (int*)(ws + 1048576);

    k_find     <<<NB, 1024, 0, stream>>>(im, ind, bhist);
    k_scatter  <<<NB, 1024, 0, stream>>>(ind, bhist, sorted, off);
    k_aggregate<<<NE * PC, 1024, 0, stream>>>(e_s, sorted, off, partial);
    k_gemm_out <<<NE * PC, 1024, 0, stream>>>(partial, W, bias, sorted, off, out);
}